// Round 10
// baseline (8767.771 us; speedup 1.0000x reference)
//
#include <hip/hip_runtime.h>

#define B_ 64
#define S_ 1024
#define H_ 768
#define GB 4    // batch groups (16 rows each)
#define CB 3    // col-blocks per group (256 cols each)

typedef short s16x8 __attribute__((ext_vector_type(8)));
typedef float f32x4 __attribute__((ext_vector_type(4)));
typedef unsigned u32x4 __attribute__((ext_vector_type(4)));

__device__ __forceinline__ unsigned short f2b(float f) {
  unsigned u = __builtin_bit_cast(unsigned, f);
  u += 0x7FFFu + ((u >> 16) & 1u);
  return (unsigned short)(u >> 16);
}
__device__ __forceinline__ float b2f(unsigned short h) {
  unsigned u = ((unsigned)h) << 16;
  return __builtin_bit_cast(float, u);
}

// tanh(x) = 1 - 2/(1+e^{2x}); exact at +-inf, ~1e-7 rel err, no branches.
__device__ __forceinline__ float fast_tanh(float x) {
  float e = __builtin_amdgcn_exp2f(x * 2.8853900817779268f);  // e^{2x}
  return 1.0f - 2.0f * __builtin_amdgcn_rcpf(1.0f + e);
}

__global__ void conv_f2b_kernel(const float* __restrict__ src,
                                unsigned short* __restrict__ dst, int n) {
  int i = (blockIdx.x * blockDim.x + threadIdx.x) * 4;
  if (i >= n) return;
  float4 v = *(const float4*)(src + i);
  unsigned long long p = (unsigned long long)f2b(v.x)
      | ((unsigned long long)f2b(v.y) << 16)
      | ((unsigned long long)f2b(v.z) << 32)
      | ((unsigned long long)f2b(v.w) << 48);
  *(unsigned long long*)(dst + i) = p;
}

__global__ void tail_kernel(const unsigned short* __restrict__ src,
                            float* __restrict__ dst, int n) {
  int i = blockIdx.x * blockDim.x + threadIdx.x;
  if (i < n) dst[i] = b2f(src[i]);
}

// C[r][n] = sum_k A[r][k] * W[n][k] + bias.  MODE0: A fp32 (x), bias1+bias2.
// MODE1: A bf16 (hseq, row-gathered: r=b*1024+s -> hseq[(s+1)*64+b]), bias1.
template <int MODE>
__global__ __launch_bounds__(256) void gemm_kernel(
    const void* __restrict__ Aptr, const unsigned short* __restrict__ Bw,
    float* __restrict__ C, const float* __restrict__ bias1,
    const float* __restrict__ bias2) {
  __shared__ unsigned short As[128 * 64];
  __shared__ unsigned short Bs[128 * 64];
  const int tid = threadIdx.x;
  const int l = tid & 63;
  const int w = tid >> 6;
  const int wm = w >> 1, wn = w & 1;
  const int r0 = blockIdx.x * 128;
  const int n0 = blockIdx.y * 128;
  const int row16 = l & 15;
  const int g4 = l >> 4;
  const int swz = (l & 7) << 3;

  const int srow = tid >> 1;
  const int shalf = (tid & 1) * 32;
  size_t a_off;
  if (MODE == 0) {
    a_off = (size_t)(r0 + srow) * 768;
  } else {
    int ar = r0 + srow;
    a_off = ((size_t)((ar & 1023) + 1) * 64 + (ar >> 10)) * 768;
  }
  const size_t b_off = (size_t)(n0 + srow) * 768;
  const int swrow = (srow & 7) << 3;

  f32x4 acc[4][4] = {};

  for (int k0 = 0; k0 < 768; k0 += 64) {
    if (MODE == 0) {
      const float* Af = (const float*)Aptr + a_off + k0 + shalf;
#pragma unroll
      for (int jj = 0; jj < 4; ++jj) {
        float4 v0 = *(const float4*)(Af + jj * 8);
        float4 v1 = *(const float4*)(Af + jj * 8 + 4);
        uint4 p;
        p.x = f2b(v0.x) | ((unsigned)f2b(v0.y) << 16);
        p.y = f2b(v0.z) | ((unsigned)f2b(v0.w) << 16);
        p.z = f2b(v1.x) | ((unsigned)f2b(v1.y) << 16);
        p.w = f2b(v1.z) | ((unsigned)f2b(v1.w) << 16);
        int c = (shalf + jj * 8) ^ swrow;
        *(uint4*)(As + srow * 64 + c) = p;
      }
    } else {
      const unsigned short* Ab = (const unsigned short*)Aptr + a_off + k0 + shalf;
#pragma unroll
      for (int jj = 0; jj < 4; ++jj) {
        uint4 p = *(const uint4*)(Ab + jj * 8);
        int c = (shalf + jj * 8) ^ swrow;
        *(uint4*)(As + srow * 64 + c) = p;
      }
    }
    {
      const unsigned short* Bb = Bw + b_off + k0 + shalf;
#pragma unroll
      for (int jj = 0; jj < 4; ++jj) {
        uint4 p = *(const uint4*)(Bb + jj * 8);
        int c = (shalf + jj * 8) ^ swrow;
        *(uint4*)(Bs + srow * 64 + c) = p;
      }
    }
    __syncthreads();
#pragma unroll
    for (int kb = 0; kb < 2; ++kb) {
      int ccol = (kb * 32 + g4 * 8) ^ swz;
      s16x8 af[4], bfr[4];
#pragma unroll
      for (int mi = 0; mi < 4; ++mi)
        af[mi] = __builtin_bit_cast(
            s16x8, *(const uint4*)(As + (wm * 64 + mi * 16 + row16) * 64 + ccol));
#pragma unroll
      for (int ni = 0; ni < 4; ++ni)
        bfr[ni] = __builtin_bit_cast(
            s16x8, *(const uint4*)(Bs + (wn * 64 + ni * 16 + row16) * 64 + ccol));
#pragma unroll
      for (int mi = 0; mi < 4; ++mi)
#pragma unroll
        for (int ni = 0; ni < 4; ++ni)
          acc[mi][ni] = __builtin_amdgcn_mfma_f32_16x16x32_bf16(
              af[mi], bfr[ni], acc[mi][ni], 0, 0, 0);
    }
    __syncthreads();
  }
#pragma unroll
  for (int ni = 0; ni < 4; ++ni) {
    int col = n0 + wn * 64 + ni * 16 + row16;
    float bv = bias1[col] + (MODE == 0 ? bias2[col] : 0.0f);
#pragma unroll
    for (int mi = 0; mi < 4; ++mi) {
      int rbase = r0 + wm * 64 + mi * 16 + g4 * 4;
#pragma unroll
      for (int i = 0; i < 4; ++i)
        C[(size_t)(rbase + i) * 768 + col] = acc[mi][ni][i] + bv;
    }
  }
}

// Persistent recurrence (R10 = R8 + pinned occupancy): 12 blocks =
// 4 batch-groups x 3 col-blocks, 1024 threads (16 waves x 16 cols).
// amdgpu_waves_per_eu(4,4): HARD max 4 waves/EU -> 128-VGPR budget and no
// incentive for the allocator to shrink to 64 (R8/R9: heuristic targeted
// 8 waves/EU -> 64-VGPR cap -> the 96-VGPR wfrag W-slice spilled to
// scratch, 3.2x regression; launch_bounds' 2nd arg only sets a MINIMUM so
// it didn't bind).  Protocol identical to R7 (proven): data-as-flag over
// sc1/IF, zero-sentinel, memset-zeroed slab, self-staged own cols, paired
// 16B stores, 4-bit XOR LDS swizzle.  Foreign poll = exactly 1 chunk/thread.
__global__ __attribute__((amdgpu_flat_work_group_size(1024, 1024),
                          amdgpu_waves_per_eu(4, 4))) void scan_kernel(
    const float* __restrict__ W_hh, const float* __restrict__ xp,
    unsigned short* __restrict__ hseq) {
  __shared__ unsigned short hs[2][16 * 768];  // 2 x 24KB
  const int tid = threadIdx.x;
  const int l = tid & 63;
  const int w = tid >> 6;              // wave 0..15
  const int bg = blockIdx.x / CB;
  const int cb = blockIdx.x % CB;
  const int b0 = bg * 16;
  const int c0 = cb * 256;
  const int row16 = l & 15;
  const int g4 = l >> 4;

  // pack W_hh fragments: A[row=l&15 (out col)][k = kb*32 + (l>>4)*8 + j]
  uint4 wfrag[24];
  {
    const float* wr = W_hh + (size_t)(c0 + w * 16 + row16) * 768;
#pragma unroll
    for (int kb = 0; kb < 24; ++kb) {
      int k0 = kb * 32 + g4 * 8;
      float4 v0 = *(const float4*)(wr + k0);
      float4 v1 = *(const float4*)(wr + k0 + 4);
      uint4 p;
      p.x = f2b(v0.x) | ((unsigned)f2b(v0.y) << 16);
      p.y = f2b(v0.z) | ((unsigned)f2b(v0.w) << 16);
      p.z = f2b(v1.x) | ((unsigned)f2b(v1.y) << 16);
      p.w = f2b(v1.z) | ((unsigned)f2b(v1.w) << 16);
      wfrag[kb] = p;
    }
  }

  // foreign-chunk geometry (t>=1): 64 foreign 16B chunks per row (own 32
  // excluded); 1024 chunks total = exactly one per thread.
  const int c08 = cb * 32;
  size_t gF;
  int lF;
  {
    int row = tid >> 6;
    int f = tid & 63;
    int col8 = f + (f >= c08 ? 32 : 0);
    gF = (size_t)(b0 + row) * 768 + col8 * 8;
    lF = row * 1536 + ((col8 * 16) ^ ((row & 15) << 4));
  }

  const size_t hcol = c0 + w * 16 + g4 * 4;
  unsigned short* hout_base = hseq + (size_t)(b0 + row16) * 768 + hcol;
  const float* xp_base = xp + (size_t)(b0 + row16) * 1024 * 768 + hcol;
  const int soff = row16 * 1536 + (((int)hcol * 2) ^ ((row16 & 15) << 4));
  const int rswz = (row16 & 15) << 4;

  for (int t = 0; t < S_; ++t) {
    char* lb = (char*)hs[t & 1];
    float4 xpv = *(const float4*)(xp_base + (size_t)t * 768);  // off crit path
    const unsigned short* hin = hseq + (size_t)t * (B_ * H_);
    if (t == 0) {
      // h0 (= zeros) pre-written by conv kernel; full slab incl. own cols.
      uint4 cv0[2];
      int nj = (tid < 512) ? 2 : 1;
#pragma unroll
      for (int j = 0; j < 2; ++j) {
        if (j < nj) {
          int ch = tid + 1024 * j;
          int row = ch / 96;
          int col8 = ch - row * 96;
          asm volatile("global_load_dwordx4 %0, %1, off sc1"
                       : "=&v"(cv0[j])
                       : "v"(hin + (size_t)(b0 + row) * 768 + col8 * 8));
        }
      }
      asm volatile("s_waitcnt vmcnt(0)" ::: "memory");
      __builtin_amdgcn_sched_barrier(0);
#pragma unroll
      for (int j = 0; j < 2; ++j) {
        if (j < nj) {
          int ch = tid + 1024 * j;
          int row = ch / 96;
          int col8 = ch - row * 96;
          *(uint4*)(lb + row * 1536 + ((col8 * 16) ^ ((row & 15) << 4))) =
              cv0[j];
        }
      }
    } else {
      uint4 cv;
      bool done = false;
      while (!__all(done)) {
        if (!done)
          asm volatile("global_load_dwordx4 %0, %1, off sc1"
                       : "=&v"(cv) : "v"(hin + gF));
        asm volatile("s_waitcnt vmcnt(0)" ::: "memory");
        __builtin_amdgcn_sched_barrier(0);  // keep checks after the waitcnt
        if (!done && (cv.x | cv.y) != 0 && (cv.z | cv.w) != 0) {
          done = true;
          *(uint4*)(lb + lF) = cv;
        }
      }
    }
    __syncthreads();

    uint4 hb[24];
    const char* rb = lb + row16 * 1536;
#pragma unroll
    for (int kb = 0; kb < 24; ++kb)
      hb[kb] = *(const uint4*)(rb + ((kb * 64 + g4 * 16) ^ rswz));

    f32x4 acc0 = {xpv.x, xpv.y, xpv.z, xpv.w};
    f32x4 acc1 = {0.f, 0.f, 0.f, 0.f};
    f32x4 acc2 = {0.f, 0.f, 0.f, 0.f};
    f32x4 acc3 = {0.f, 0.f, 0.f, 0.f};
#pragma unroll
    for (int kb = 0; kb < 24; kb += 4) {
      acc0 = __builtin_amdgcn_mfma_f32_16x16x32_bf16(
          __builtin_bit_cast(s16x8, wfrag[kb]),
          __builtin_bit_cast(s16x8, hb[kb]), acc0, 0, 0, 0);
      acc1 = __builtin_amdgcn_mfma_f32_16x16x32_bf16(
          __builtin_bit_cast(s16x8, wfrag[kb + 1]),
          __builtin_bit_cast(s16x8, hb[kb + 1]), acc1, 0, 0, 0);
      acc2 = __builtin_amdgcn_mfma_f32_16x16x32_bf16(
          __builtin_bit_cast(s16x8, wfrag[kb + 2]),
          __builtin_bit_cast(s16x8, hb[kb + 2]), acc2, 0, 0, 0);
      acc3 = __builtin_amdgcn_mfma_f32_16x16x32_bf16(
          __builtin_bit_cast(s16x8, wfrag[kb + 3]),
          __builtin_bit_cast(s16x8, hb[kb + 3]), acc3, 0, 0, 0);
    }
    f32x4 g = (acc0 + acc1) + (acc2 + acc3);
    float t0 = fast_tanh(g[0]), t1 = fast_tanh(g[1]);
    float t2 = fast_tanh(g[2]), t3 = fast_tanh(g[3]);
    unsigned long long pk = (unsigned long long)f2b(t0)
        | ((unsigned long long)f2b(t1) << 16)
        | ((unsigned long long)f2b(t2) << 32)
        | ((unsigned long long)f2b(t3) << 48);
    if (pk == 0) pk = 1;  // readiness sentinel: never store an all-zero word

    // self-stage own cols for step t+1 (single writer of this LDS region)
    *(unsigned long long*)((char*)hs[(t + 1) & 1] + soff) = pk;

    // paired 16B global store: lane pairs (l, l^16) -> even-g4 lane stores 8 cols
    unsigned long long po = __shfl(pk, l ^ 16);
    if ((g4 & 1) == 0) {
      u32x4 st;
      st[0] = (unsigned)pk;
      st[1] = (unsigned)(pk >> 32);
      st[2] = (unsigned)po;
      st[3] = (unsigned)(po >> 32);
      asm volatile("global_store_dwordx4 %0, %1, off sc1" ::"v"(
                       hout_base + (size_t)(t + 1) * (B_ * H_)),
                   "v"(st)
                   : "memory");
    }
    // no trailing barrier: double-buffered LDS; a wave cannot reach step t+2
    // staging before all siblings' step-t reads are done (its t+2 poll
    // transitively requires every sibling's t+1 global store).
  }
}

extern "C" void kernel_launch(void* const* d_in, const int* in_sizes, int n_in,
                              void* d_out, int out_size, void* d_ws,
                              size_t ws_size, hipStream_t stream) {
  const float* hidden = (const float*)d_in[0];
  const float* x = (const float*)d_in[1];
  const float* W_ih = (const float*)d_in[2];
  const float* W_hh = (const float*)d_in[3];
  const float* b_ih = (const float*)d_in[4];
  const float* b_hh = (const float*)d_in[5];
  const float* W_fc = (const float*)d_in[6];
  const float* b_fc = (const float*)d_in[7];
  float* out = (float*)d_out;
  float* xp = out;  // xp [B*S][768] fp32 reuses the logits region (overwritten later)

  char* ws = (char*)d_ws;
  unsigned short* hseq = (unsigned short*)ws;  // [(S+1)][B][H] bf16
  size_t hseq_elems = (size_t)(S_ + 1) * B_ * H_;
  unsigned short* wih_b = hseq + hseq_elems;
  unsigned short* wfc_b = wih_b + 768 * 768;

  // zero h[1..S]: required every launch (data-as-flag poll; ws is not
  // re-poisoned between replays)
  (void)hipMemsetAsync(hseq + (size_t)B_ * H_, 0, (size_t)S_ * B_ * H_ * 2,
                       stream);
  conv_f2b_kernel<<<576, 256, 0, stream>>>(W_ih, wih_b, 768 * 768);
  conv_f2b_kernel<<<576, 256, 0, stream>>>(W_fc, wfc_b, 768 * 768);
  conv_f2b_kernel<<<48, 256, 0, stream>>>(hidden, hseq, B_ * H_);
  dim3 grid(512, 6);
  gemm_kernel<0><<<grid, 256, 0, stream>>>(x, wih_b, xp, b_ih, b_hh);
  scan_kernel<<<GB * CB, 1024, 0, stream>>>(W_hh, xp, hseq);
  gemm_kernel<1><<<grid, 256, 0, stream>>>(hseq, wfc_b, out, b_fc, nullptr);
  tail_kernel<<<192, 256, 0, stream>>>(hseq + (size_t)S_ * B_ * H_,
                                       out + (size_t)65536 * 768, B_ * H_);
}

// Round 12
// 4925.751 us; speedup vs baseline: 1.7800x; 1.7800x over previous
//
#include <hip/hip_runtime.h>

#define B_ 64
#define S_ 1024
#define H_ 768
#define GB 4    // batch groups (16 rows each)
#define CB 6    // col-blocks per group (128 cols each)

typedef short s16x8 __attribute__((ext_vector_type(8)));
typedef float f32x4 __attribute__((ext_vector_type(4)));
typedef unsigned u32x4 __attribute__((ext_vector_type(4)));

__device__ __forceinline__ unsigned short f2b(float f) {
  unsigned u = __builtin_bit_cast(unsigned, f);
  u += 0x7FFFu + ((u >> 16) & 1u);
  return (unsigned short)(u >> 16);
}
__device__ __forceinline__ float b2f(unsigned short h) {
  unsigned u = ((unsigned)h) << 16;
  return __builtin_bit_cast(float, u);
}

// tanh(x) = 1 - 2/(1+e^{2x}); exact at +-inf, ~1e-7 rel err, no branches.
__device__ __forceinline__ float fast_tanh(float x) {
  float e = __builtin_amdgcn_exp2f(x * 2.8853900817779268f);  // e^{2x}
  return 1.0f - 2.0f * __builtin_amdgcn_rcpf(1.0f + e);
}

__global__ void conv_f2b_kernel(const float* __restrict__ src,
                                unsigned short* __restrict__ dst, int n) {
  int i = (blockIdx.x * blockDim.x + threadIdx.x) * 4;
  if (i >= n) return;
  float4 v = *(const float4*)(src + i);
  unsigned long long p = (unsigned long long)f2b(v.x)
      | ((unsigned long long)f2b(v.y) << 16)
      | ((unsigned long long)f2b(v.z) << 32)
      | ((unsigned long long)f2b(v.w) << 48);
  *(unsigned long long*)(dst + i) = p;
}

__global__ void tail_kernel(const unsigned short* __restrict__ src,
                            float* __restrict__ dst, int n) {
  int i = blockIdx.x * blockDim.x + threadIdx.x;
  if (i < n) dst[i] = b2f(src[i]);
}

// C[r][n] = sum_k A[r][k] * W[n][k] + bias.  MODE0: A fp32 (x), bias1+bias2.
// MODE1: A bf16 (hseq, row-gathered: r=b*1024+s -> hseq[(s+1)*64+b]), bias1.
template <int MODE>
__global__ __launch_bounds__(256) void gemm_kernel(
    const void* __restrict__ Aptr, const unsigned short* __restrict__ Bw,
    float* __restrict__ C, const float* __restrict__ bias1,
    const float* __restrict__ bias2) {
  __shared__ unsigned short As[128 * 64];
  __shared__ unsigned short Bs[128 * 64];
  const int tid = threadIdx.x;
  const int l = tid & 63;
  const int w = tid >> 6;
  const int wm = w >> 1, wn = w & 1;
  const int r0 = blockIdx.x * 128;
  const int n0 = blockIdx.y * 128;
  const int row16 = l & 15;
  const int g4 = l >> 4;
  const int swz = (l & 7) << 3;

  const int srow = tid >> 1;
  const int shalf = (tid & 1) * 32;
  size_t a_off;
  if (MODE == 0) {
    a_off = (size_t)(r0 + srow) * 768;
  } else {
    int ar = r0 + srow;
    a_off = ((size_t)((ar & 1023) + 1) * 64 + (ar >> 10)) * 768;
  }
  const size_t b_off = (size_t)(n0 + srow) * 768;
  const int swrow = (srow & 7) << 3;

  f32x4 acc[4][4] = {};

  for (int k0 = 0; k0 < 768; k0 += 64) {
    if (MODE == 0) {
      const float* Af = (const float*)Aptr + a_off + k0 + shalf;
#pragma unroll
      for (int jj = 0; jj < 4; ++jj) {
        float4 v0 = *(const float4*)(Af + jj * 8);
        float4 v1 = *(const float4*)(Af + jj * 8 + 4);
        uint4 p;
        p.x = f2b(v0.x) | ((unsigned)f2b(v0.y) << 16);
        p.y = f2b(v0.z) | ((unsigned)f2b(v0.w) << 16);
        p.z = f2b(v1.x) | ((unsigned)f2b(v1.y) << 16);
        p.w = f2b(v1.z) | ((unsigned)f2b(v1.w) << 16);
        int c = (shalf + jj * 8) ^ swrow;
        *(uint4*)(As + srow * 64 + c) = p;
      }
    } else {
      const unsigned short* Ab = (const unsigned short*)Aptr + a_off + k0 + shalf;
#pragma unroll
      for (int jj = 0; jj < 4; ++jj) {
        uint4 p = *(const uint4*)(Ab + jj * 8);
        int c = (shalf + jj * 8) ^ swrow;
        *(uint4*)(As + srow * 64 + c) = p;
      }
    }
    {
      const unsigned short* Bb = Bw + b_off + k0 + shalf;
#pragma unroll
      for (int jj = 0; jj < 4; ++jj) {
        uint4 p = *(const uint4*)(Bb + jj * 8);
        int c = (shalf + jj * 8) ^ swrow;
        *(uint4*)(Bs + srow * 64 + c) = p;
      }
    }
    __syncthreads();
#pragma unroll
    for (int kb = 0; kb < 2; ++kb) {
      int ccol = (kb * 32 + g4 * 8) ^ swz;
      s16x8 af[4], bfr[4];
#pragma unroll
      for (int mi = 0; mi < 4; ++mi)
        af[mi] = __builtin_bit_cast(
            s16x8, *(const uint4*)(As + (wm * 64 + mi * 16 + row16) * 64 + ccol));
#pragma unroll
      for (int ni = 0; ni < 4; ++ni)
        bfr[ni] = __builtin_bit_cast(
            s16x8, *(const uint4*)(Bs + (wn * 64 + ni * 16 + row16) * 64 + ccol));
#pragma unroll
      for (int mi = 0; mi < 4; ++mi)
#pragma unroll
        for (int ni = 0; ni < 4; ++ni)
          acc[mi][ni] = __builtin_amdgcn_mfma_f32_16x16x32_bf16(
              af[mi], bfr[ni], acc[mi][ni], 0, 0, 0);
    }
    __syncthreads();
  }
#pragma unroll
  for (int ni = 0; ni < 4; ++ni) {
    int col = n0 + wn * 64 + ni * 16 + row16;
    float bv = bias1[col] + (MODE == 0 ? bias2[col] : 0.0f);
#pragma unroll
    for (int mi = 0; mi < 4; ++mi) {
      int rbase = r0 + wm * 64 + mi * 16 + g4 * 4;
#pragma unroll
      for (int i = 0; i < 4; ++i)
        C[(size_t)(rbase + i) * 768 + col] = acc[mi][ni][i] + bv;
    }
  }
}

// Persistent recurrence (R12 = R7 + hint-flag): 24 blocks = 4 batch-groups x
// 6 col-blocks, 512 threads (8 waves x 16 cols).  Correctness protocol is
// EXACTLY R7's proven data-as-flag (sc1/IF, zero-sentinel, memset-zeroed
// slab, self-staged own cols, paired 16B stores, 4-bit XOR LDS swizzle).
// R12 adds a pure-HINT progress flag that carries NO correctness weight:
//   producer: each wave's lane0 atomicAdd(flags[t+1][bg],1) right after
//             issuing its stores (no drain) -> target 48 = 8 waves x 6 blks
//   consumer: spins on flags[t][bg]>=48 (all lanes same addr -> ONE 4B
//             request per wave per period vs 30K chunk re-reads per sweep),
//             THEN runs the unchanged verify/sweep loop (first sweep = one
//             coalesced bulk load that normally verifies complete).
// Early/lost/reordered flags only cost time (fall back to R7 sweeps);
// deadlock-free since producers inc unconditionally after compute.
__global__ __launch_bounds__(512) void scan_kernel(
    const float* __restrict__ W_hh, const float* __restrict__ xp,
    unsigned short* __restrict__ hseq, int* __restrict__ flags) {
  __shared__ unsigned short hs[2][16 * 768];  // 2 x 24KB
  const int tid = threadIdx.x;
  const int l = tid & 63;
  const int w = tid >> 6;
  const int bg = blockIdx.x / CB;
  const int cb = blockIdx.x % CB;
  const int b0 = bg * 16;
  const int c0 = cb * 128;
  const int row16 = l & 15;
  const int g4 = l >> 4;

  // pack W_hh fragments: A[row=l&15 (out col)][k = kb*32 + (l>>4)*8 + j]
  uint4 wfrag[24];
  {
    const float* wr = W_hh + (size_t)(c0 + w * 16 + row16) * 768;
#pragma unroll
    for (int kb = 0; kb < 24; ++kb) {
      int k0 = kb * 32 + g4 * 8;
      float4 v0 = *(const float4*)(wr + k0);
      float4 v1 = *(const float4*)(wr + k0 + 4);
      uint4 p;
      p.x = f2b(v0.x) | ((unsigned)f2b(v0.y) << 16);
      p.y = f2b(v0.z) | ((unsigned)f2b(v0.w) << 16);
      p.z = f2b(v1.x) | ((unsigned)f2b(v1.y) << 16);
      p.w = f2b(v1.z) | ((unsigned)f2b(v1.w) << 16);
      wfrag[kb] = p;
    }
  }

  // foreign-chunk geometry (t>=1): 80 foreign 16B chunks per row (own 16
  // excluded).  1280 = 512x2 + 256: threads <256 take a 3rd chunk.
  const int c08 = cb * 16;
  const int nch = (tid < 256) ? 3 : 2;
  size_t gF[3];
  int lF[3];
#pragma unroll
  for (int j = 0; j < 3; ++j) {
    int fi = (j < 2) ? (tid + 512 * j) : (1024 + (tid & 255));
    int row = fi / 80;
    int f = fi - row * 80;
    int col8 = f + (f >= c08 ? 16 : 0);
    gF[j] = (size_t)(b0 + row) * 768 + col8 * 8;
    lF[j] = row * 1536 + ((col8 * 16) ^ ((row & 15) << 4));
  }

  const size_t hcol = c0 + w * 16 + g4 * 4;
  unsigned short* hout_base = hseq + (size_t)(b0 + row16) * 768 + hcol;
  const float* xp_base = xp + (size_t)(b0 + row16) * 1024 * 768 + hcol;
  const int soff = row16 * 1536 + (((int)hcol * 2) ^ ((row16 & 15) << 4));
  const int rswz = (row16 & 15) << 4;

  for (int t = 0; t < S_; ++t) {
    char* lb = (char*)hs[t & 1];
    float4 xpv = *(const float4*)(xp_base + (size_t)t * 768);  // off crit path
    const unsigned short* hin = hseq + (size_t)t * (B_ * H_);
    if (t == 0) {
      // h0 (= zeros) pre-written by conv kernel; full slab incl. own cols.
      uint4 cv0[3];
#pragma unroll
      for (int j = 0; j < 3; ++j) {
        int ch = tid + 512 * j;
        int row = ch / 96;
        int col8 = ch - row * 96;
        asm volatile("global_load_dwordx4 %0, %1, off sc1"
                     : "=&v"(cv0[j])
                     : "v"(hin + (size_t)(b0 + row) * 768 + col8 * 8));
      }
      asm volatile("s_waitcnt vmcnt(0)" ::: "memory");
      __builtin_amdgcn_sched_barrier(0);
#pragma unroll
      for (int j = 0; j < 3; ++j) {
        int ch = tid + 512 * j;
        int row = ch / 96;
        int col8 = ch - row * 96;
        *(uint4*)(lb + row * 1536 + ((col8 * 16) ^ ((row & 15) << 4))) = cv0[j];
      }
    } else {
      // hint-gate: wait until ~all producer waves have issued their stores.
      // Pure hint: correctness comes from the verify sweeps below.
      {
        const int* fp = flags + t * GB + bg;
        int fv;
        do {
          fv = __hip_atomic_load(fp, __ATOMIC_RELAXED, __HIP_MEMORY_SCOPE_AGENT);
        } while (fv < 48);
      }
      uint4 cv[3];
      unsigned done = 0;
      const unsigned full = (nch == 3) ? 7u : 3u;
      while (done != full) {
        if (!(done & 1))
          asm volatile("global_load_dwordx4 %0, %1, off sc1"
                       : "=&v"(cv[0]) : "v"(hin + gF[0]));
        if (!(done & 2))
          asm volatile("global_load_dwordx4 %0, %1, off sc1"
                       : "=&v"(cv[1]) : "v"(hin + gF[1]));
        if (nch == 3 && !(done & 4))
          asm volatile("global_load_dwordx4 %0, %1, off sc1"
                       : "=&v"(cv[2]) : "v"(hin + gF[2]));
        asm volatile("s_waitcnt vmcnt(0)" ::: "memory");
        __builtin_amdgcn_sched_barrier(0);  // keep checks after the waitcnt
        if (!(done & 1) && (cv[0].x | cv[0].y) != 0 && (cv[0].z | cv[0].w) != 0) {
          done |= 1;
          *(uint4*)(lb + lF[0]) = cv[0];
        }
        if (!(done & 2) && (cv[1].x | cv[1].y) != 0 && (cv[1].z | cv[1].w) != 0) {
          done |= 2;
          *(uint4*)(lb + lF[1]) = cv[1];
        }
        if (nch == 3 && !(done & 4) && (cv[2].x | cv[2].y) != 0 &&
            (cv[2].z | cv[2].w) != 0) {
          done |= 4;
          *(uint4*)(lb + lF[2]) = cv[2];
        }
      }
    }
    __syncthreads();

    uint4 hb[24];
    const char* rb = lb + row16 * 1536;
#pragma unroll
    for (int kb = 0; kb < 24; ++kb)
      hb[kb] = *(const uint4*)(rb + ((kb * 64 + g4 * 16) ^ rswz));

    f32x4 acc0 = {xpv.x, xpv.y, xpv.z, xpv.w};
    f32x4 acc1 = {0.f, 0.f, 0.f, 0.f};
    f32x4 acc2 = {0.f, 0.f, 0.f, 0.f};
    f32x4 acc3 = {0.f, 0.f, 0.f, 0.f};
#pragma unroll
    for (int kb = 0; kb < 24; kb += 4) {
      acc0 = __builtin_amdgcn_mfma_f32_16x16x32_bf16(
          __builtin_bit_cast(s16x8, wfrag[kb]),
          __builtin_bit_cast(s16x8, hb[kb]), acc0, 0, 0, 0);
      acc1 = __builtin_amdgcn_mfma_f32_16x16x32_bf16(
          __builtin_bit_cast(s16x8, wfrag[kb + 1]),
          __builtin_bit_cast(s16x8, hb[kb + 1]), acc1, 0, 0, 0);
      acc2 = __builtin_amdgcn_mfma_f32_16x16x32_bf16(
          __builtin_bit_cast(s16x8, wfrag[kb + 2]),
          __builtin_bit_cast(s16x8, hb[kb + 2]), acc2, 0, 0, 0);
      acc3 = __builtin_amdgcn_mfma_f32_16x16x32_bf16(
          __builtin_bit_cast(s16x8, wfrag[kb + 3]),
          __builtin_bit_cast(s16x8, hb[kb + 3]), acc3, 0, 0, 0);
    }
    f32x4 g = (acc0 + acc1) + (acc2 + acc3);
    float t0 = fast_tanh(g[0]), t1 = fast_tanh(g[1]);
    float t2 = fast_tanh(g[2]), t3 = fast_tanh(g[3]);
    unsigned long long pk = (unsigned long long)f2b(t0)
        | ((unsigned long long)f2b(t1) << 16)
        | ((unsigned long long)f2b(t2) << 32)
        | ((unsigned long long)f2b(t3) << 48);
    if (pk == 0) pk = 1;  // readiness sentinel: never store an all-zero word

    // self-stage own cols for step t+1 (single writer of this LDS region)
    *(unsigned long long*)((char*)hs[(t + 1) & 1] + soff) = pk;

    // paired 16B global store: lane pairs (l, l^16) -> even-g4 lane stores 8 cols
    unsigned long long po = __shfl(pk, l ^ 16);
    if ((g4 & 1) == 0) {
      u32x4 st;
      st[0] = (unsigned)pk;
      st[1] = (unsigned)(pk >> 32);
      st[2] = (unsigned)po;
      st[3] = (unsigned)(po >> 32);
      asm volatile("global_store_dwordx4 %0, %1, off sc1" ::"v"(
                       hout_base + (size_t)(t + 1) * (B_ * H_)),
                   "v"(st)
                   : "memory");
    }
    // hint inc: one per wave, fire-and-forget (no drain; consumers verify)
    if (l == 0) {
      __hip_atomic_fetch_add(flags + (t + 1) * GB + bg, 1, __ATOMIC_RELAXED,
                             __HIP_MEMORY_SCOPE_AGENT);
    }
    // no trailing barrier: double-buffered LDS; a wave cannot reach step t+2
    // staging before all siblings' step-t reads are done (its t+2 poll
    // transitively requires every sibling's t+1 global store).
  }
}

extern "C" void kernel_launch(void* const* d_in, const int* in_sizes, int n_in,
                              void* d_out, int out_size, void* d_ws,
                              size_t ws_size, hipStream_t stream) {
  const float* hidden = (const float*)d_in[0];
  const float* x = (const float*)d_in[1];
  const float* W_ih = (const float*)d_in[2];
  const float* W_hh = (const float*)d_in[3];
  const float* b_ih = (const float*)d_in[4];
  const float* b_hh = (const float*)d_in[5];
  const float* W_fc = (const float*)d_in[6];
  const float* b_fc = (const float*)d_in[7];
  float* out = (float*)d_out;
  float* xp = out;  // xp [B*S][768] fp32 reuses the logits region (overwritten later)

  char* ws = (char*)d_ws;
  unsigned short* hseq = (unsigned short*)ws;  // [(S+1)][B][H] bf16
  size_t hseq_elems = (size_t)(S_ + 1) * B_ * H_;
  unsigned short* wih_b = hseq + hseq_elems;
  unsigned short* wfc_b = wih_b + 768 * 768;
  int* flags = (int*)(wfc_b + 768 * 768);  // [(S+1)][GB] hint counters

  // zero h[1..S] + flags: required every launch (data-as-flag poll + hint
  // counters; ws is not re-poisoned between replays)
  (void)hipMemsetAsync(hseq + (size_t)B_ * H_, 0, (size_t)S_ * B_ * H_ * 2,
                       stream);
  (void)hipMemsetAsync(flags, 0, (size_t)(S_ + 1) * GB * sizeof(int), stream);
  conv_f2b_kernel<<<576, 256, 0, stream>>>(W_ih, wih_b, 768 * 768);
  conv_f2b_kernel<<<576, 256, 0, stream>>>(W_fc, wfc_b, 768 * 768);
  conv_f2b_kernel<<<48, 256, 0, stream>>>(hidden, hseq, B_ * H_);
  dim3 grid(512, 6);
  gemm_kernel<0><<<grid, 256, 0, stream>>>(x, wih_b, xp, b_ih, b_hh);
  scan_kernel<<<GB * CB, 512, 0, stream>>>(W_hh, xp, hseq, flags);
  gemm_kernel<1><<<grid, 256, 0, stream>>>(hseq, wfc_b, out, b_fc, nullptr);
  tail_kernel<<<192, 256, 0, stream>>>(hseq + (size_t)S_ * B_ * H_,
                                       out + (size_t)65536 * 768, B_ * H_);
}

// Round 13
// 2789.073 us; speedup vs baseline: 3.1436x; 1.7661x over previous
//
#include <hip/hip_runtime.h>

#define B_ 64
#define S_ 1024
#define H_ 768
#define GB 8    // batch groups (8 rows each)
#define CB 6    // col-blocks per group (128 cols each)

typedef short s16x8 __attribute__((ext_vector_type(8)));
typedef float f32x4 __attribute__((ext_vector_type(4)));
typedef unsigned u32x4 __attribute__((ext_vector_type(4)));

__device__ __forceinline__ unsigned short f2b(float f) {
  unsigned u = __builtin_bit_cast(unsigned, f);
  u += 0x7FFFu + ((u >> 16) & 1u);
  return (unsigned short)(u >> 16);
}
__device__ __forceinline__ float b2f(unsigned short h) {
  unsigned u = ((unsigned)h) << 16;
  return __builtin_bit_cast(float, u);
}

// tanh(x) = 1 - 2/(1+e^{2x}); exact at +-inf, ~1e-7 rel err, no branches.
__device__ __forceinline__ float fast_tanh(float x) {
  float e = __builtin_amdgcn_exp2f(x * 2.8853900817779268f);  // e^{2x}
  return 1.0f - 2.0f * __builtin_amdgcn_rcpf(1.0f + e);
}

__global__ void conv_f2b_kernel(const float* __restrict__ src,
                                unsigned short* __restrict__ dst, int n) {
  int i = (blockIdx.x * blockDim.x + threadIdx.x) * 4;
  if (i >= n) return;
  float4 v = *(const float4*)(src + i);
  unsigned long long p = (unsigned long long)f2b(v.x)
      | ((unsigned long long)f2b(v.y) << 16)
      | ((unsigned long long)f2b(v.z) << 32)
      | ((unsigned long long)f2b(v.w) << 48);
  *(unsigned long long*)(dst + i) = p;
}

__global__ void tail_kernel(const unsigned short* __restrict__ src,
                            float* __restrict__ dst, int n) {
  int i = blockIdx.x * blockDim.x + threadIdx.x;
  if (i < n) dst[i] = b2f(src[i]);
}

// C[r][n] = sum_k A[r][k] * W[n][k] + bias.  MODE0: A fp32 (x), bias1+bias2.
// MODE1: A bf16 (hseq, row-gathered: r=b*1024+s -> hseq[(s+1)*64+b]), bias1.
template <int MODE>
__global__ __launch_bounds__(256) void gemm_kernel(
    const void* __restrict__ Aptr, const unsigned short* __restrict__ Bw,
    float* __restrict__ C, const float* __restrict__ bias1,
    const float* __restrict__ bias2) {
  __shared__ unsigned short As[128 * 64];
  __shared__ unsigned short Bs[128 * 64];
  const int tid = threadIdx.x;
  const int l = tid & 63;
  const int w = tid >> 6;
  const int wm = w >> 1, wn = w & 1;
  const int r0 = blockIdx.x * 128;
  const int n0 = blockIdx.y * 128;
  const int row16 = l & 15;
  const int g4 = l >> 4;
  const int swz = (l & 7) << 3;

  const int srow = tid >> 1;
  const int shalf = (tid & 1) * 32;
  size_t a_off;
  if (MODE == 0) {
    a_off = (size_t)(r0 + srow) * 768;
  } else {
    int ar = r0 + srow;
    a_off = ((size_t)((ar & 1023) + 1) * 64 + (ar >> 10)) * 768;
  }
  const size_t b_off = (size_t)(n0 + srow) * 768;
  const int swrow = (srow & 7) << 3;

  f32x4 acc[4][4] = {};

  for (int k0 = 0; k0 < 768; k0 += 64) {
    if (MODE == 0) {
      const float* Af = (const float*)Aptr + a_off + k0 + shalf;
#pragma unroll
      for (int jj = 0; jj < 4; ++jj) {
        float4 v0 = *(const float4*)(Af + jj * 8);
        float4 v1 = *(const float4*)(Af + jj * 8 + 4);
        uint4 p;
        p.x = f2b(v0.x) | ((unsigned)f2b(v0.y) << 16);
        p.y = f2b(v0.z) | ((unsigned)f2b(v0.w) << 16);
        p.z = f2b(v1.x) | ((unsigned)f2b(v1.y) << 16);
        p.w = f2b(v1.z) | ((unsigned)f2b(v1.w) << 16);
        int c = (shalf + jj * 8) ^ swrow;
        *(uint4*)(As + srow * 64 + c) = p;
      }
    } else {
      const unsigned short* Ab = (const unsigned short*)Aptr + a_off + k0 + shalf;
#pragma unroll
      for (int jj = 0; jj < 4; ++jj) {
        uint4 p = *(const uint4*)(Ab + jj * 8);
        int c = (shalf + jj * 8) ^ swrow;
        *(uint4*)(As + srow * 64 + c) = p;
      }
    }
    {
      const unsigned short* Bb = Bw + b_off + k0 + shalf;
#pragma unroll
      for (int jj = 0; jj < 4; ++jj) {
        uint4 p = *(const uint4*)(Bb + jj * 8);
        int c = (shalf + jj * 8) ^ swrow;
        *(uint4*)(Bs + srow * 64 + c) = p;
      }
    }
    __syncthreads();
#pragma unroll
    for (int kb = 0; kb < 2; ++kb) {
      int ccol = (kb * 32 + g4 * 8) ^ swz;
      s16x8 af[4], bfr[4];
#pragma unroll
      for (int mi = 0; mi < 4; ++mi)
        af[mi] = __builtin_bit_cast(
            s16x8, *(const uint4*)(As + (wm * 64 + mi * 16 + row16) * 64 + ccol));
#pragma unroll
      for (int ni = 0; ni < 4; ++ni)
        bfr[ni] = __builtin_bit_cast(
            s16x8, *(const uint4*)(Bs + (wn * 64 + ni * 16 + row16) * 64 + ccol));
#pragma unroll
      for (int mi = 0; mi < 4; ++mi)
#pragma unroll
        for (int ni = 0; ni < 4; ++ni)
          acc[mi][ni] = __builtin_amdgcn_mfma_f32_16x16x32_bf16(
              af[mi], bfr[ni], acc[mi][ni], 0, 0, 0);
    }
    __syncthreads();
  }
#pragma unroll
  for (int ni = 0; ni < 4; ++ni) {
    int col = n0 + wn * 64 + ni * 16 + row16;
    float bv = bias1[col] + (MODE == 0 ? bias2[col] : 0.0f);
#pragma unroll
    for (int mi = 0; mi < 4; ++mi) {
      int rbase = r0 + wm * 64 + mi * 16 + g4 * 4;
#pragma unroll
      for (int i = 0; i < 4; ++i)
        C[(size_t)(rbase + i) * 768 + col] = acc[mi][ni][i] + bv;
    }
  }
}

// Persistent recurrence (R13): 48 blocks = 8 batch-groups (8 rows) x 6
// col-blocks (128 cols), 512 threads (8 waves x 16 cols).  Protocol is
// EXACTLY R7's proven data-as-flag (sc1/IF, zero-sentinel, memset-zeroed
// slab, self-staged own cols, paired 16B stores, XOR LDS swizzle) — the
// R12 hint-gate was removed (it serialized the step, 2x regression; R7's
// overlapped polling is the right structure).  R13 delta: 8-row groups ->
// foreign poll = 1 chunk/thread (640 chunks, 512 thr) so the sweep period
// halves and the catch delay shrinks.  MFMA B-rows 8..15 duplicate rows
// 0..7; stores gated to row16<8 (wasted flops are free at 0.7% MfmaUtil).
__global__ __launch_bounds__(512) void scan_kernel(
    const float* __restrict__ W_hh, const float* __restrict__ xp,
    unsigned short* __restrict__ hseq) {
  __shared__ unsigned short hs[2][8 * 768];  // 2 x 12KB
  const int tid = threadIdx.x;
  const int l = tid & 63;
  const int w = tid >> 6;
  const int bg = blockIdx.x / CB;  // 0..7
  const int cb = blockIdx.x % CB;  // 0..5
  const int b0 = bg * 8;
  const int c0 = cb * 128;
  const int row16 = l & 15;
  const int row8 = row16 & 7;
  const int g4 = l >> 4;

  // pack W_hh fragments: A[row=l&15 (out col)][k = kb*32 + (l>>4)*8 + j]
  uint4 wfrag[24];
  {
    const float* wr = W_hh + (size_t)(c0 + w * 16 + row16) * 768;
#pragma unroll
    for (int kb = 0; kb < 24; ++kb) {
      int k0 = kb * 32 + g4 * 8;
      float4 v0 = *(const float4*)(wr + k0);
      float4 v1 = *(const float4*)(wr + k0 + 4);
      uint4 p;
      p.x = f2b(v0.x) | ((unsigned)f2b(v0.y) << 16);
      p.y = f2b(v0.z) | ((unsigned)f2b(v0.w) << 16);
      p.z = f2b(v1.x) | ((unsigned)f2b(v1.y) << 16);
      p.w = f2b(v1.z) | ((unsigned)f2b(v1.w) << 16);
      wfrag[kb] = p;
    }
  }

  // foreign-chunk geometry (t>=1): 80 foreign 16B chunks per row (own 16
  // excluded) x 8 rows = 640 = 512 + 128: threads <128 take a 2nd chunk.
  const int c08 = cb * 16;
  const int nch = (tid < 128) ? 2 : 1;
  size_t gF[2];
  int lF[2];
#pragma unroll
  for (int j = 0; j < 2; ++j) {
    int fi = (j == 0) ? tid : (512 + (tid & 127));  // j=1 used only if tid<128
    int row = fi / 80;
    int f = fi - row * 80;
    int col8 = f + (f >= c08 ? 16 : 0);
    gF[j] = (size_t)(b0 + row) * 768 + col8 * 8;
    lF[j] = row * 1536 + ((col8 * 16) ^ ((row & 7) << 4));
  }

  const size_t hcol = c0 + w * 16 + g4 * 4;
  unsigned short* hout_base = hseq + (size_t)(b0 + row8) * 768 + hcol;
  const float* xp_base = xp + (size_t)(b0 + row8) * 1024 * 768 + hcol;
  const int soff = row8 * 1536 + (((int)hcol * 2) ^ (row8 << 4));
  const int rswz = row8 << 4;
  const bool owner = (row16 < 8);

  for (int t = 0; t < S_; ++t) {
    char* lb = (char*)hs[t & 1];
    float4 xpv = *(const float4*)(xp_base + (size_t)t * 768);  // off crit path
    const unsigned short* hin = hseq + (size_t)t * (B_ * H_);
    if (t == 0) {
      // h0 (= zeros) pre-written by conv kernel; full slab = 768 chunks:
      // every thread 1, threads <256 a 2nd.
      uint4 cv0[2];
      int nj = (tid < 256) ? 2 : 1;
#pragma unroll
      for (int j = 0; j < 2; ++j) {
        if (j < nj) {
          int ch = (j == 0) ? tid : (512 + (tid & 255));
          int row = ch / 96;
          int col8 = ch - row * 96;
          asm volatile("global_load_dwordx4 %0, %1, off sc1"
                       : "=&v"(cv0[j])
                       : "v"(hin + (size_t)(b0 + row) * 768 + col8 * 8));
        }
      }
      asm volatile("s_waitcnt vmcnt(0)" ::: "memory");
      __builtin_amdgcn_sched_barrier(0);
#pragma unroll
      for (int j = 0; j < 2; ++j) {
        if (j < nj) {
          int ch = (j == 0) ? tid : (512 + (tid & 255));
          int row = ch / 96;
          int col8 = ch - row * 96;
          *(uint4*)(lb + row * 1536 + ((col8 * 16) ^ ((row & 7) << 4))) =
              cv0[j];
        }
      }
    } else {
      uint4 cv[2];
      unsigned done = 0;
      const unsigned full = (nch == 2) ? 3u : 1u;
      while (done != full) {
        if (!(done & 1))
          asm volatile("global_load_dwordx4 %0, %1, off sc1"
                       : "=&v"(cv[0]) : "v"(hin + gF[0]));
        if (nch == 2 && !(done & 2))
          asm volatile("global_load_dwordx4 %0, %1, off sc1"
                       : "=&v"(cv[1]) : "v"(hin + gF[1]));
        asm volatile("s_waitcnt vmcnt(0)" ::: "memory");
        __builtin_amdgcn_sched_barrier(0);  // keep checks after the waitcnt
        if (!(done & 1) && (cv[0].x | cv[0].y) != 0 && (cv[0].z | cv[0].w) != 0) {
          done |= 1;
          *(uint4*)(lb + lF[0]) = cv[0];
        }
        if (nch == 2 && !(done & 2) && (cv[1].x | cv[1].y) != 0 &&
            (cv[1].z | cv[1].w) != 0) {
          done |= 2;
          *(uint4*)(lb + lF[1]) = cv[1];
        }
      }
    }
    __syncthreads();

    uint4 hb[24];
    const char* rb = lb + row8 * 1536;
#pragma unroll
    for (int kb = 0; kb < 24; ++kb)
      hb[kb] = *(const uint4*)(rb + ((kb * 64 + g4 * 16) ^ rswz));

    f32x4 acc0 = {xpv.x, xpv.y, xpv.z, xpv.w};
    f32x4 acc1 = {0.f, 0.f, 0.f, 0.f};
    f32x4 acc2 = {0.f, 0.f, 0.f, 0.f};
    f32x4 acc3 = {0.f, 0.f, 0.f, 0.f};
#pragma unroll
    for (int kb = 0; kb < 24; kb += 4) {
      acc0 = __builtin_amdgcn_mfma_f32_16x16x32_bf16(
          __builtin_bit_cast(s16x8, wfrag[kb]),
          __builtin_bit_cast(s16x8, hb[kb]), acc0, 0, 0, 0);
      acc1 = __builtin_amdgcn_mfma_f32_16x16x32_bf16(
          __builtin_bit_cast(s16x8, wfrag[kb + 1]),
          __builtin_bit_cast(s16x8, hb[kb + 1]), acc1, 0, 0, 0);
      acc2 = __builtin_amdgcn_mfma_f32_16x16x32_bf16(
          __builtin_bit_cast(s16x8, wfrag[kb + 2]),
          __builtin_bit_cast(s16x8, hb[kb + 2]), acc2, 0, 0, 0);
      acc3 = __builtin_amdgcn_mfma_f32_16x16x32_bf16(
          __builtin_bit_cast(s16x8, wfrag[kb + 3]),
          __builtin_bit_cast(s16x8, hb[kb + 3]), acc3, 0, 0, 0);
    }
    f32x4 g = (acc0 + acc1) + (acc2 + acc3);
    float t0 = fast_tanh(g[0]), t1 = fast_tanh(g[1]);
    float t2 = fast_tanh(g[2]), t3 = fast_tanh(g[3]);
    unsigned long long pk = (unsigned long long)f2b(t0)
        | ((unsigned long long)f2b(t1) << 16)
        | ((unsigned long long)f2b(t2) << 32)
        | ((unsigned long long)f2b(t3) << 48);
    if (pk == 0) pk = 1;  // readiness sentinel: never store an all-zero word

    // self-stage own cols for step t+1 (single writer; rows 0..7 only)
    if (owner) *(unsigned long long*)((char*)hs[(t + 1) & 1] + soff) = pk;

    // paired 16B global store: lanes (l, l^16) -> even-g4 owner lane stores
    unsigned long long po = __shfl(pk, l ^ 16);
    if (owner && (g4 & 1) == 0) {
      u32x4 st;
      st[0] = (unsigned)pk;
      st[1] = (unsigned)(pk >> 32);
      st[2] = (unsigned)po;
      st[3] = (unsigned)(po >> 32);
      asm volatile("global_store_dwordx4 %0, %1, off sc1" ::"v"(
                       hout_base + (size_t)(t + 1) * (B_ * H_)),
                   "v"(st)
                   : "memory");
    }
    // no trailing barrier: double-buffered LDS; a wave cannot reach step t+2
    // staging before all siblings' step-t reads are done (its t+2 poll
    // transitively requires every other group-block's t+1 stores, which
    // require this block's waves' t+1 stores, which follow their t reads).
  }
}

extern "C" void kernel_launch(void* const* d_in, const int* in_sizes, int n_in,
                              void* d_out, int out_size, void* d_ws,
                              size_t ws_size, hipStream_t stream) {
  const float* hidden = (const float*)d_in[0];
  const float* x = (const float*)d_in[1];
  const float* W_ih = (const float*)d_in[2];
  const float* W_hh = (const float*)d_in[3];
  const float* b_ih = (const float*)d_in[4];
  const float* b_hh = (const float*)d_in[5];
  const float* W_fc = (const float*)d_in[6];
  const float* b_fc = (const float*)d_in[7];
  float* out = (float*)d_out;
  float* xp = out;  // xp [B*S][768] fp32 reuses the logits region (overwritten later)

  char* ws = (char*)d_ws;
  unsigned short* hseq = (unsigned short*)ws;  // [(S+1)][B][H] bf16
  size_t hseq_elems = (size_t)(S_ + 1) * B_ * H_;
  unsigned short* wih_b = hseq + hseq_elems;
  unsigned short* wfc_b = wih_b + 768 * 768;

  // zero h[1..S]: required every launch (data-as-flag poll; ws is not
  // re-poisoned between replays)
  (void)hipMemsetAsync(hseq + (size_t)B_ * H_, 0, (size_t)S_ * B_ * H_ * 2,
                       stream);
  conv_f2b_kernel<<<576, 256, 0, stream>>>(W_ih, wih_b, 768 * 768);
  conv_f2b_kernel<<<576, 256, 0, stream>>>(W_fc, wfc_b, 768 * 768);
  conv_f2b_kernel<<<48, 256, 0, stream>>>(hidden, hseq, B_ * H_);
  dim3 grid(512, 6);
  gemm_kernel<0><<<grid, 256, 0, stream>>>(x, wih_b, xp, b_ih, b_hh);
  scan_kernel<<<GB * CB, 512, 0, stream>>>(W_hh, xp, hseq);
  gemm_kernel<1><<<grid, 256, 0, stream>>>(hseq, wfc_b, out, b_fc, nullptr);
  tail_kernel<<<192, 256, 0, stream>>>(hseq + (size_t)S_ * B_ * H_,
                                       out + (size_t)65536 * 768, B_ * H_);
}

// Round 14
// 2575.093 us; speedup vs baseline: 3.4048x; 1.0831x over previous
//
#include <hip/hip_runtime.h>

#define B_ 64
#define S_ 1024
#define H_ 768
#define GB 8    // batch groups (8 rows each)
#define CB 6    // col-blocks per group (128 cols each)

typedef short s16x8 __attribute__((ext_vector_type(8)));
typedef float f32x4 __attribute__((ext_vector_type(4)));
typedef unsigned u32x4 __attribute__((ext_vector_type(4)));

__device__ __forceinline__ unsigned short f2b(float f) {
  unsigned u = __builtin_bit_cast(unsigned, f);
  u += 0x7FFFu + ((u >> 16) & 1u);
  return (unsigned short)(u >> 16);
}
__device__ __forceinline__ float b2f(unsigned short h) {
  unsigned u = ((unsigned)h) << 16;
  return __builtin_bit_cast(float, u);
}

// tanh(x) = 1 - 2/(1+e^{2x}); exact at +-inf, ~1e-7 rel err, no branches.
__device__ __forceinline__ float fast_tanh(float x) {
  float e = __builtin_amdgcn_exp2f(x * 2.8853900817779268f);  // e^{2x}
  return 1.0f - 2.0f * __builtin_amdgcn_rcpf(1.0f + e);
}

__global__ void conv_f2b_kernel(const float* __restrict__ src,
                                unsigned short* __restrict__ dst, int n) {
  int i = (blockIdx.x * blockDim.x + threadIdx.x) * 4;
  if (i >= n) return;
  float4 v = *(const float4*)(src + i);
  unsigned long long p = (unsigned long long)f2b(v.x)
      | ((unsigned long long)f2b(v.y) << 16)
      | ((unsigned long long)f2b(v.z) << 32)
      | ((unsigned long long)f2b(v.w) << 48);
  *(unsigned long long*)(dst + i) = p;
}

__global__ void tail_kernel(const unsigned short* __restrict__ src,
                            float* __restrict__ dst, int n) {
  int i = blockIdx.x * blockDim.x + threadIdx.x;
  if (i < n) dst[i] = b2f(src[i]);
}

// C[r][n] = sum_k A[r][k] * W[n][k] + bias.  MODE0: A fp32 (x), bias1+bias2.
// MODE1: A bf16 (hseq, row-gathered: r=b*1024+s -> hseq[(s+1)*64+b]), bias1.
template <int MODE>
__global__ __launch_bounds__(256) void gemm_kernel(
    const void* __restrict__ Aptr, const unsigned short* __restrict__ Bw,
    float* __restrict__ C, const float* __restrict__ bias1,
    const float* __restrict__ bias2) {
  __shared__ unsigned short As[128 * 64];
  __shared__ unsigned short Bs[128 * 64];
  const int tid = threadIdx.x;
  const int l = tid & 63;
  const int w = tid >> 6;
  const int wm = w >> 1, wn = w & 1;
  const int r0 = blockIdx.x * 128;
  const int n0 = blockIdx.y * 128;
  const int row16 = l & 15;
  const int g4 = l >> 4;
  const int swz = (l & 7) << 3;

  const int srow = tid >> 1;
  const int shalf = (tid & 1) * 32;
  size_t a_off;
  if (MODE == 0) {
    a_off = (size_t)(r0 + srow) * 768;
  } else {
    int ar = r0 + srow;
    a_off = ((size_t)((ar & 1023) + 1) * 64 + (ar >> 10)) * 768;
  }
  const size_t b_off = (size_t)(n0 + srow) * 768;
  const int swrow = (srow & 7) << 3;

  f32x4 acc[4][4] = {};

  for (int k0 = 0; k0 < 768; k0 += 64) {
    if (MODE == 0) {
      const float* Af = (const float*)Aptr + a_off + k0 + shalf;
#pragma unroll
      for (int jj = 0; jj < 4; ++jj) {
        float4 v0 = *(const float4*)(Af + jj * 8);
        float4 v1 = *(const float4*)(Af + jj * 8 + 4);
        uint4 p;
        p.x = f2b(v0.x) | ((unsigned)f2b(v0.y) << 16);
        p.y = f2b(v0.z) | ((unsigned)f2b(v0.w) << 16);
        p.z = f2b(v1.x) | ((unsigned)f2b(v1.y) << 16);
        p.w = f2b(v1.z) | ((unsigned)f2b(v1.w) << 16);
        int c = (shalf + jj * 8) ^ swrow;
        *(uint4*)(As + srow * 64 + c) = p;
      }
    } else {
      const unsigned short* Ab = (const unsigned short*)Aptr + a_off + k0 + shalf;
#pragma unroll
      for (int jj = 0; jj < 4; ++jj) {
        uint4 p = *(const uint4*)(Ab + jj * 8);
        int c = (shalf + jj * 8) ^ swrow;
        *(uint4*)(As + srow * 64 + c) = p;
      }
    }
    {
      const unsigned short* Bb = Bw + b_off + k0 + shalf;
#pragma unroll
      for (int jj = 0; jj < 4; ++jj) {
        uint4 p = *(const uint4*)(Bb + jj * 8);
        int c = (shalf + jj * 8) ^ swrow;
        *(uint4*)(Bs + srow * 64 + c) = p;
      }
    }
    __syncthreads();
#pragma unroll
    for (int kb = 0; kb < 2; ++kb) {
      int ccol = (kb * 32 + g4 * 8) ^ swz;
      s16x8 af[4], bfr[4];
#pragma unroll
      for (int mi = 0; mi < 4; ++mi)
        af[mi] = __builtin_bit_cast(
            s16x8, *(const uint4*)(As + (wm * 64 + mi * 16 + row16) * 64 + ccol));
#pragma unroll
      for (int ni = 0; ni < 4; ++ni)
        bfr[ni] = __builtin_bit_cast(
            s16x8, *(const uint4*)(Bs + (wn * 64 + ni * 16 + row16) * 64 + ccol));
#pragma unroll
      for (int mi = 0; mi < 4; ++mi)
#pragma unroll
        for (int ni = 0; ni < 4; ++ni)
          acc[mi][ni] = __builtin_amdgcn_mfma_f32_16x16x32_bf16(
              af[mi], bfr[ni], acc[mi][ni], 0, 0, 0);
    }
    __syncthreads();
  }
#pragma unroll
  for (int ni = 0; ni < 4; ++ni) {
    int col = n0 + wn * 64 + ni * 16 + row16;
    float bv = bias1[col] + (MODE == 0 ? bias2[col] : 0.0f);
#pragma unroll
    for (int mi = 0; mi < 4; ++mi) {
      int rbase = r0 + wm * 64 + mi * 16 + g4 * 4;
#pragma unroll
      for (int i = 0; i < 4; ++i)
        C[(size_t)(rbase + i) * 768 + col] = acc[mi][ni][i] + bv;
    }
  }
}

// Persistent recurrence (R14 = R13 + 16-slot read swizzle): 48 blocks =
// 8 batch-groups (8 rows) x 6 col-blocks (128 cols), 512 threads.
// Protocol = R7/R13's proven data-as-flag (sc1/IF, zero-sentinel,
// memset-zeroed slab, self-staged own cols, paired 16B stores).
// R14 delta: read-side LDS swizzle key is row16<<4 (16 slots) while the
// write key stays row8<<4.  For row16<8 read==write (correct data); for
// row16>=8 the lane reads a DIFFERENT valid 16B chunk (garbage) — but
// those lanes feed MFMA B-cols 8..15 whose outputs are never stored
// (owner gating), so the data is don't-care.  This makes all 64 lane
// addresses distinct, eliminating R13's b128 same-address serialization
// (SQ_LDS_BANK_CONFLICT 3.8e7 -> expected ~1e6, the R7 profile).
__global__ __launch_bounds__(512) void scan_kernel(
    const float* __restrict__ W_hh, const float* __restrict__ xp,
    unsigned short* __restrict__ hseq) {
  __shared__ unsigned short hs[2][8 * 768];  // 2 x 12KB
  const int tid = threadIdx.x;
  const int l = tid & 63;
  const int w = tid >> 6;
  const int bg = blockIdx.x / CB;  // 0..7
  const int cb = blockIdx.x % CB;  // 0..5
  const int b0 = bg * 8;
  const int c0 = cb * 128;
  const int row16 = l & 15;
  const int row8 = row16 & 7;
  const int g4 = l >> 4;

  // pack W_hh fragments: A[row=l&15 (out col)][k = kb*32 + (l>>4)*8 + j]
  uint4 wfrag[24];
  {
    const float* wr = W_hh + (size_t)(c0 + w * 16 + row16) * 768;
#pragma unroll
    for (int kb = 0; kb < 24; ++kb) {
      int k0 = kb * 32 + g4 * 8;
      float4 v0 = *(const float4*)(wr + k0);
      float4 v1 = *(const float4*)(wr + k0 + 4);
      uint4 p;
      p.x = f2b(v0.x) | ((unsigned)f2b(v0.y) << 16);
      p.y = f2b(v0.z) | ((unsigned)f2b(v0.w) << 16);
      p.z = f2b(v1.x) | ((unsigned)f2b(v1.y) << 16);
      p.w = f2b(v1.z) | ((unsigned)f2b(v1.w) << 16);
      wfrag[kb] = p;
    }
  }

  // foreign-chunk geometry (t>=1): 80 foreign 16B chunks per row (own 16
  // excluded) x 8 rows = 640 = 512 + 128: threads <128 take a 2nd chunk.
  const int c08 = cb * 16;
  const int nch = (tid < 128) ? 2 : 1;
  size_t gF[2];
  int lF[2];
#pragma unroll
  for (int j = 0; j < 2; ++j) {
    int fi = (j == 0) ? tid : (512 + (tid & 127));  // j=1 used only if tid<128
    int row = fi / 80;
    int f = fi - row * 80;
    int col8 = f + (f >= c08 ? 16 : 0);
    gF[j] = (size_t)(b0 + row) * 768 + col8 * 8;
    lF[j] = row * 1536 + ((col8 * 16) ^ ((row & 7) << 4));
  }

  const size_t hcol = c0 + w * 16 + g4 * 4;
  unsigned short* hout_base = hseq + (size_t)(b0 + row8) * 768 + hcol;
  const float* xp_base = xp + (size_t)(b0 + row8) * 1024 * 768 + hcol;
  const int soff = row8 * 1536 + (((int)hcol * 2) ^ (row8 << 4));
  const int rswz = row16 << 4;  // 16-slot key; row16>=8 reads don't-care data
  const bool owner = (row16 < 8);

  for (int t = 0; t < S_; ++t) {
    char* lb = (char*)hs[t & 1];
    float4 xpv = *(const float4*)(xp_base + (size_t)t * 768);  // off crit path
    const unsigned short* hin = hseq + (size_t)t * (B_ * H_);
    if (t == 0) {
      // h0 (= zeros) pre-written by conv kernel; full slab = 768 chunks:
      // every thread 1, threads <256 a 2nd.
      uint4 cv0[2];
      int nj = (tid < 256) ? 2 : 1;
#pragma unroll
      for (int j = 0; j < 2; ++j) {
        if (j < nj) {
          int ch = (j == 0) ? tid : (512 + (tid & 255));
          int row = ch / 96;
          int col8 = ch - row * 96;
          asm volatile("global_load_dwordx4 %0, %1, off sc1"
                       : "=&v"(cv0[j])
                       : "v"(hin + (size_t)(b0 + row) * 768 + col8 * 8));
        }
      }
      asm volatile("s_waitcnt vmcnt(0)" ::: "memory");
      __builtin_amdgcn_sched_barrier(0);
#pragma unroll
      for (int j = 0; j < 2; ++j) {
        if (j < nj) {
          int ch = (j == 0) ? tid : (512 + (tid & 255));
          int row = ch / 96;
          int col8 = ch - row * 96;
          *(uint4*)(lb + row * 1536 + ((col8 * 16) ^ ((row & 7) << 4))) =
              cv0[j];
        }
      }
    } else {
      uint4 cv[2];
      unsigned done = 0;
      const unsigned full = (nch == 2) ? 3u : 1u;
      while (done != full) {
        if (!(done & 1))
          asm volatile("global_load_dwordx4 %0, %1, off sc1"
                       : "=&v"(cv[0]) : "v"(hin + gF[0]));
        if (nch == 2 && !(done & 2))
          asm volatile("global_load_dwordx4 %0, %1, off sc1"
                       : "=&v"(cv[1]) : "v"(hin + gF[1]));
        asm volatile("s_waitcnt vmcnt(0)" ::: "memory");
        __builtin_amdgcn_sched_barrier(0);  // keep checks after the waitcnt
        if (!(done & 1) && (cv[0].x | cv[0].y) != 0 && (cv[0].z | cv[0].w) != 0) {
          done |= 1;
          *(uint4*)(lb + lF[0]) = cv[0];
        }
        if (nch == 2 && !(done & 2) && (cv[1].x | cv[1].y) != 0 &&
            (cv[1].z | cv[1].w) != 0) {
          done |= 2;
          *(uint4*)(lb + lF[1]) = cv[1];
        }
      }
    }
    __syncthreads();

    uint4 hb[24];
    const char* rb = lb + row8 * 1536;
#pragma unroll
    for (int kb = 0; kb < 24; ++kb)
      hb[kb] = *(const uint4*)(rb + ((kb * 64 + g4 * 16) ^ rswz));

    f32x4 acc0 = {xpv.x, xpv.y, xpv.z, xpv.w};
    f32x4 acc1 = {0.f, 0.f, 0.f, 0.f};
    f32x4 acc2 = {0.f, 0.f, 0.f, 0.f};
    f32x4 acc3 = {0.f, 0.f, 0.f, 0.f};
#pragma unroll
    for (int kb = 0; kb < 24; kb += 4) {
      acc0 = __builtin_amdgcn_mfma_f32_16x16x32_bf16(
          __builtin_bit_cast(s16x8, wfrag[kb]),
          __builtin_bit_cast(s16x8, hb[kb]), acc0, 0, 0, 0);
      acc1 = __builtin_amdgcn_mfma_f32_16x16x32_bf16(
          __builtin_bit_cast(s16x8, wfrag[kb + 1]),
          __builtin_bit_cast(s16x8, hb[kb + 1]), acc1, 0, 0, 0);
      acc2 = __builtin_amdgcn_mfma_f32_16x16x32_bf16(
          __builtin_bit_cast(s16x8, wfrag[kb + 2]),
          __builtin_bit_cast(s16x8, hb[kb + 2]), acc2, 0, 0, 0);
      acc3 = __builtin_amdgcn_mfma_f32_16x16x32_bf16(
          __builtin_bit_cast(s16x8, wfrag[kb + 3]),
          __builtin_bit_cast(s16x8, hb[kb + 3]), acc3, 0, 0, 0);
    }
    f32x4 g = (acc0 + acc1) + (acc2 + acc3);
    float t0 = fast_tanh(g[0]), t1 = fast_tanh(g[1]);
    float t2 = fast_tanh(g[2]), t3 = fast_tanh(g[3]);
    unsigned long long pk = (unsigned long long)f2b(t0)
        | ((unsigned long long)f2b(t1) << 16)
        | ((unsigned long long)f2b(t2) << 32)
        | ((unsigned long long)f2b(t3) << 48);
    if (pk == 0) pk = 1;  // readiness sentinel: never store an all-zero word

    // self-stage own cols for step t+1 (single writer; rows 0..7 only)
    if (owner) *(unsigned long long*)((char*)hs[(t + 1) & 1] + soff) = pk;

    // paired 16B global store: lanes (l, l^16) -> even-g4 owner lane stores
    unsigned long long po = __shfl(pk, l ^ 16);
    if (owner && (g4 & 1) == 0) {
      u32x4 st;
      st[0] = (unsigned)pk;
      st[1] = (unsigned)(pk >> 32);
      st[2] = (unsigned)po;
      st[3] = (unsigned)(po >> 32);
      asm volatile("global_store_dwordx4 %0, %1, off sc1" ::"v"(
                       hout_base + (size_t)(t + 1) * (B_ * H_)),
                   "v"(st)
                   : "memory");
    }
    // no trailing barrier: double-buffered LDS; a wave cannot reach step t+2
    // staging before all siblings' step-t reads are done (its t+2 poll
    // transitively requires every other group-block's t+1 stores, which
    // require this block's waves' t+1 stores, which follow their t reads).
  }
}

extern "C" void kernel_launch(void* const* d_in, const int* in_sizes, int n_in,
                              void* d_out, int out_size, void* d_ws,
                              size_t ws_size, hipStream_t stream) {
  const float* hidden = (const float*)d_in[0];
  const float* x = (const float*)d_in[1];
  const float* W_ih = (const float*)d_in[2];
  const float* W_hh = (const float*)d_in[3];
  const float* b_ih = (const float*)d_in[4];
  const float* b_hh = (const float*)d_in[5];
  const float* W_fc = (const float*)d_in[6];
  const float* b_fc = (const float*)d_in[7];
  float* out = (float*)d_out;
  float* xp = out;  // xp [B*S][768] fp32 reuses the logits region (overwritten later)

  char* ws = (char*)d_ws;
  unsigned short* hseq = (unsigned short*)ws;  // [(S+1)][B][H] bf16
  size_t hseq_elems = (size_t)(S_ + 1) * B_ * H_;
  unsigned short* wih_b = hseq + hseq_elems;
  unsigned short* wfc_b = wih_b + 768 * 768;

  // zero h[1..S]: required every launch (data-as-flag poll; ws is not
  // re-poisoned between replays)
  (void)hipMemsetAsync(hseq + (size_t)B_ * H_, 0, (size_t)S_ * B_ * H_ * 2,
                       stream);
  conv_f2b_kernel<<<576, 256, 0, stream>>>(W_ih, wih_b, 768 * 768);
  conv_f2b_kernel<<<576, 256, 0, stream>>>(W_fc, wfc_b, 768 * 768);
  conv_f2b_kernel<<<48, 256, 0, stream>>>(hidden, hseq, B_ * H_);
  dim3 grid(512, 6);
  gemm_kernel<0><<<grid, 256, 0, stream>>>(x, wih_b, xp, b_ih, b_hh);
  scan_kernel<<<GB * CB, 512, 0, stream>>>(W_hh, xp, hseq);
  gemm_kernel<1><<<grid, 256, 0, stream>>>(hseq, wfc_b, out, b_fc, nullptr);
  tail_kernel<<<192, 256, 0, stream>>>(hseq + (size_t)S_ * B_ * H_,
                                       out + (size_t)65536 * 768, B_ * H_);
}